// Round 15
// baseline (317.388 us; speedup 1.0000x reference)
//
#include <hip/hip_runtime.h>
#include <hip/hip_bf16.h>

#define N_NODES 50000
#define N_EDGES 500000
#define N_GRAPHS 64
#define FDIM 256   // H*HID
#define NHEAD 8
#define NC 10
#define SLOPE 0.2f
#define MPAD 50048  // N_NODES rounded up to 64
#define SCAN_NB ((N_NODES + 1023) / 1024)   // 49 blocks of 1024 elements

typedef __attribute__((ext_vector_type(8))) short bf16x8;
typedef __attribute__((ext_vector_type(4))) float f32x4;
typedef __attribute__((ext_vector_type(2))) float f32x2;

__device__ __forceinline__ unsigned short f2bf(float f) {
  unsigned x = __float_as_uint(f);
  x += 0x7fff + ((x >> 16) & 1);   // RNE
  return (unsigned short)(x >> 16);
}
__device__ __forceinline__ float b2f(unsigned short u) {
  return __uint_as_float((unsigned)u << 16);
}

// ---------------- CSR build: histogram + fused weight transposes ----------------
__global__ void hist_cast_kernel(const int* __restrict__ dst, int* __restrict__ deg,
                                 const float* __restrict__ W1, const float* __restrict__ W2,
                                 unsigned short* __restrict__ Wt1, unsigned short* __restrict__ Wt2,
                                 int E) {
  int e = blockIdx.x * blockDim.x + threadIdx.x;
  if (e < E) atomicAdd(&deg[dst[e]], 1);
  // first 98304 threads also do the weight transposes (independent work)
  if (e < 256 * 128) {
    int n = e / 128, k = e % 128;
    Wt1[(size_t)n * 128 + k] = f2bf(W1[(size_t)k * 256 + n]);
  } else if (e < 256 * 128 + 256 * 256) {
    int t2 = e - 256 * 128;
    int n = t2 / 256, k = t2 % 256;
    Wt2[(size_t)n * 256 + k] = f2bf(W2[(size_t)k * 256 + n]);
  }
}

// ---- multi-block exclusive scan of deg[0..n) -> rowstart[0..n] ----
__global__ void scan_local_kernel(const int* __restrict__ deg, int* __restrict__ rowstart,
                                  int* __restrict__ bsum, int n) {
  __shared__ int ws[4];
  int t = threadIdx.x, lane = t & 63, w = t >> 6;
  int base = blockIdx.x * 1024 + t * 4;
  int4 v = make_int4(0, 0, 0, 0);
  if (base + 3 < n) {
    v = *(const int4*)(deg + base);
  } else {
    if (base + 0 < n) v.x = deg[base + 0];
    if (base + 1 < n) v.y = deg[base + 1];
    if (base + 2 < n) v.z = deg[base + 2];
    if (base + 3 < n) v.w = deg[base + 3];
  }
  int s = v.x + v.y + v.z + v.w;
  int x = s;
  #pragma unroll
  for (int off = 1; off < 64; off <<= 1) {
    int y = __shfl_up(x, off);
    if (lane >= off) x += y;
  }
  if (lane == 63) ws[w] = x;
  __syncthreads();
  int woff = 0;
  #pragma unroll
  for (int i = 0; i < 4; ++i) woff += (i < w) ? ws[i] : 0;
  int excl = woff + x - s;
  int4 o;
  o.x = excl;
  o.y = excl + v.x;
  o.z = excl + v.x + v.y;
  o.w = excl + v.x + v.y + v.z;
  if (base + 3 < n) {
    *(int4*)(rowstart + base) = o;
  } else {
    if (base + 0 < n) rowstart[base + 0] = o.x;
    if (base + 1 < n) rowstart[base + 1] = o.y;
    if (base + 2 < n) rowstart[base + 2] = o.z;
    if (base + 3 < n) rowstart[base + 3] = o.w;
  }
  if (t == 255) bsum[blockIdx.x] = woff + x;
}

// phase 2+3 + graph_bounds fused: each block wave-scans the 49 block sums,
// adds offsets, fills gstart. rowstart[n]=E.
__global__ void scan_add_gb_kernel(int* __restrict__ rowstart, const int* __restrict__ bsum,
                                   const int* __restrict__ n2g, int* __restrict__ gstart, int n) {
  __shared__ int boff[64];
  int t = threadIdx.x;
  if (t < 64) {
    int v = (t < SCAN_NB) ? bsum[t] : 0;
    int x = v;
    #pragma unroll
    for (int off = 1; off < 64; off <<= 1) {
      int y = __shfl_up(x, off);
      if (t >= off) x += y;
    }
    boff[t] = x - v;   // exclusive prefix
  }
  __syncthreads();
  int i = blockIdx.x * blockDim.x + threadIdx.x;
  if (i < n) {
    rowstart[i] += boff[i >> 10];
    int g1 = n2g[i];
    int g0 = (i == 0) ? -1 : n2g[i - 1];
    for (int g = g0 + 1; g <= g1; ++g) gstart[g] = i;
    if (i == n - 1) {
      for (int g = g1 + 1; g <= N_GRAPHS; ++g) gstart[g] = n;
    }
  }
  if (i == 0) rowstart[n] = N_EDGES;
}

__global__ void scatter_kernel(const int* __restrict__ src, const int* __restrict__ dst,
                               const int* __restrict__ rowstart, int* __restrict__ cursor,
                               int* __restrict__ esrc, int E) {
  int e = blockIdx.x * blockDim.x + threadIdx.x;
  if (e >= E) return;
  int d = dst[e];
  int p = atomicAdd(&cursor[d], 1);
  esrc[rowstart[d] + p] = src[e];
}

// ---------------- LDS-staged MFMA GEMM + fused attention logits ----------------
// fs output FP8 e4m3 (HW packed): 12.8 MB -> 3x better L2 coverage for the
// edge gather. el/er computed from fp32 acc (alpha weights unaffected).
template<int K, bool AF32>
__global__ void gemm_mfma(const void* __restrict__ Avoid,
                          const unsigned short* __restrict__ Wt,
                          unsigned char* __restrict__ fs,
                          const float* __restrict__ al, const float* __restrict__ ar,
                          float* __restrict__ el, float* __restrict__ er, int nrows) {
  constexpr int KC = K / 32;
  __shared__ __align__(16) unsigned short Albs[64 * 32];    // [row][32k] 4 KB
  __shared__ __align__(16) unsigned short Wlds[256 * 32];   // [n][32k] 16 KB
  const float* Af = (const float*)Avoid;
  const unsigned short* Ab = (const unsigned short*)Avoid;
  int t = threadIdx.x;
  int lane = t & 63;
  int w = t >> 6;
  int row0 = blockIdx.x * 64;
  int m = lane & 15;
  int q = lane >> 4;
  float4 a32[2];
  bf16x8 a16;
  bf16x8 wtr[4];
  int arow = t >> 2, apiece = t & 3;
  int agrow = min(row0 + arow, nrows - 1);
  int frow0 = t >> 3, fquad0 = t & 7;
  int frow1 = (256 + t) >> 3, fquad1 = t & 7;
  int fgrow0 = min(row0 + frow0, nrows - 1);
  int fgrow1 = min(row0 + frow1, nrows - 1);

  auto stage = [&](int kc) {
    if (AF32) {
      a32[0] = *(const float4*)(Af + (size_t)fgrow0 * K + kc * 32 + fquad0 * 4);
      a32[1] = *(const float4*)(Af + (size_t)fgrow1 * K + kc * 32 + fquad1 * 4);
    } else {
      a16 = *(const bf16x8*)(Ab + (size_t)agrow * K + kc * 32 + apiece * 8);
    }
    #pragma unroll
    for (int j = 0; j < 4; ++j) {
      int row = j * 64 + (t >> 2);
      wtr[j] = *(const bf16x8*)(Wt + (size_t)row * K + kc * 32 + (t & 3) * 8);
    }
  };
  auto commit = [&]() {
    if (AF32) {
      ushort4 o0, o1;
      o0.x = f2bf(a32[0].x); o0.y = f2bf(a32[0].y); o0.z = f2bf(a32[0].z); o0.w = f2bf(a32[0].w);
      o1.x = f2bf(a32[1].x); o1.y = f2bf(a32[1].y); o1.z = f2bf(a32[1].z); o1.w = f2bf(a32[1].w);
      *(ushort4*)(Albs + frow0 * 32 + fquad0 * 4) = o0;
      *(ushort4*)(Albs + frow1 * 32 + fquad1 * 4) = o1;
    } else {
      *(bf16x8*)(Albs + arow * 32 + apiece * 8) = a16;
    }
    #pragma unroll
    for (int j = 0; j < 4; ++j) {
      int row = j * 64 + (t >> 2);
      *(bf16x8*)(Wlds + row * 32 + (t & 3) * 8) = wtr[j];
    }
  };

  f32x4 acc[16];
  #pragma unroll
  for (int nt = 0; nt < 16; ++nt) acc[nt] = (f32x4){0.f, 0.f, 0.f, 0.f};

  stage(0);
  commit();
  for (int kc = 0; kc < KC; ++kc) {
    __syncthreads();
    if (kc + 1 < KC) stage(kc + 1);
    bf16x8 af = *(const bf16x8*)(Albs + (w * 16 + m) * 32 + q * 8);
    #pragma unroll
    for (int nt = 0; nt < 16; ++nt) {
      bf16x8 bfv = *(const bf16x8*)(Wlds + (nt * 16 + m) * 32 + q * 8);
      acc[nt] = __builtin_amdgcn_mfma_f32_16x16x32_bf16(bfv, af, acc[nt], 0, 0, 0);
    }
    __syncthreads();
    if (kc + 1 < KC) commit();
  }

  int node = row0 + w * 16 + m;
  float elh[NHEAD], erh[NHEAD];
  #pragma unroll
  for (int h = 0; h < NHEAD; ++h) { elh[h] = 0.f; erh[h] = 0.f; }
  #pragma unroll
  for (int nt = 0; nt < 16; ++nt) {
    int h = nt >> 1;
    int c0 = (nt & 1) * 16 + q * 4;
    float4 a4 = *(const float4*)(al + h * 32 + c0);
    float4 r4 = *(const float4*)(ar + h * 32 + c0);
    elh[h] += acc[nt][0] * a4.x + acc[nt][1] * a4.y + acc[nt][2] * a4.z + acc[nt][3] * a4.w;
    erh[h] += acc[nt][0] * r4.x + acc[nt][1] * r4.y + acc[nt][2] * r4.z + acc[nt][3] * r4.w;
  }
  #pragma unroll
  for (int h = 0; h < NHEAD; ++h) {
    elh[h] += __shfl_xor(elh[h], 16); elh[h] += __shfl_xor(elh[h], 32);
    erh[h] += __shfl_xor(erh[h], 16); erh[h] += __shfl_xor(erh[h], 32);
  }
  // fs store: pack 4 fp32 -> 4 fp8 bytes (one dword per nt)
  #pragma unroll
  for (int nt = 0; nt < 16; ++nt) {
    int pk = 0;
    pk = __builtin_amdgcn_cvt_pk_fp8_f32(acc[nt][0], acc[nt][1], pk, false);
    pk = __builtin_amdgcn_cvt_pk_fp8_f32(acc[nt][2], acc[nt][3], pk, true);
    *(unsigned*)(fs + (size_t)node * 256 + nt * 16 + q * 4) = (unsigned)pk;
  }
  *(float2*)(el + (size_t)node * NHEAD + 2 * q) = make_float2(elh[2 * q], elh[2 * q + 1]);
  *(float2*)(er + (size_t)node * NHEAD + 2 * q) = make_float2(erh[2 * q], erh[2 * q + 1]);
}

// ---------------- fused edge softmax + aggregation: one wave per dst node ----------------
// Lane-specialized weights; dual accumulators; fs gather in FP8.
template<bool RELU>
__global__ __launch_bounds__(256, 8)
void edge_agg_kernel(const int* __restrict__ rowstart, const int* __restrict__ esrc,
                     const float* __restrict__ el, const float* __restrict__ er,
                     const unsigned char* __restrict__ fs,
                     const float* __restrict__ bias,
                     unsigned short* __restrict__ out, int nnodes) {
  int gid = blockIdx.x * blockDim.x + threadIdx.x;
  int v = gid >> 6;
  int lane = threadIdx.x & 63;
  if (v >= nnodes) return;
  int h = lane >> 3;       // consumer head
  int t8 = lane >> 3;      // producer edge slot
  int hh = lane & 7;       // producer head
  int row0 = rowstart[v];
  int deg = rowstart[v + 1] - row0;
  float er_w = er[v * NHEAD + hh];
  const unsigned char* fsl = fs + lane * 4;   // 4 fp8 bytes per lane
  const float* elp = el;
  float4 acc0 = make_float4(0.f, 0.f, 0.f, 0.f);
  float4 acc1 = make_float4(0.f, 0.f, 0.f, 0.f);
  float ws0 = 0.f, ws1 = 0.f;
  for (int base = 0; base < deg; base += 64) {
    int mm = min(deg - base, 64);
    int li = (lane < mm) ? lane : (mm - 1);
    int es = esrc[row0 + base + li];
    for (int j0 = 0; j0 < mm; j0 += 8) {
      int sj = __shfl(es, min(j0 + t8, mm - 1));
      float x = elp[(unsigned)sj * 8u + hh] + er_w;
      x = fmaxf(x, SLOPE * x);
      float wp = __expf(x);
      if (j0 + t8 >= mm) wp = 0.f;
      float wt[8]; unsigned f[8];
      #pragma unroll
      for (int t = 0; t < 8; ++t) wt[t] = __shfl(wp, t * 8 + h);
      #pragma unroll
      for (int t = 0; t < 8; ++t) {
        int s = __shfl(es, min(j0 + t, mm - 1));
        f[t] = *(const unsigned*)(fsl + ((unsigned)s << 8));   // 256 B row stride
      }
      #pragma unroll
      for (int t = 0; t < 8; ++t) {
        float wgt = wt[t];
        f32x2 lo = __builtin_amdgcn_cvt_pk_f32_fp8(f[t], false);
        f32x2 hi = __builtin_amdgcn_cvt_pk_f32_fp8(f[t], true);
        if (t & 1) {
          ws1 += wgt;
          acc1.x = fmaf(wgt, lo.x, acc1.x);
          acc1.y = fmaf(wgt, lo.y, acc1.y);
          acc1.z = fmaf(wgt, hi.x, acc1.z);
          acc1.w = fmaf(wgt, hi.y, acc1.w);
        } else {
          ws0 += wgt;
          acc0.x = fmaf(wgt, lo.x, acc0.x);
          acc0.y = fmaf(wgt, lo.y, acc0.y);
          acc0.z = fmaf(wgt, hi.x, acc0.z);
          acc0.w = fmaf(wgt, hi.y, acc0.w);
        }
      }
    }
  }
  float wsum = ws0 + ws1;
  float4 acc;
  acc.x = acc0.x + acc1.x; acc.y = acc0.y + acc1.y;
  acc.z = acc0.z + acc1.z; acc.w = acc0.w + acc1.w;
  float rdenom = (deg > 0) ? (1.0f / wsum) : 0.f;
  const float4 b = *(const float4*)(bias + lane * 4);
  acc.x = fmaf(acc.x, rdenom, b.x);
  acc.y = fmaf(acc.y, rdenom, b.y);
  acc.z = fmaf(acc.z, rdenom, b.z);
  acc.w = fmaf(acc.w, rdenom, b.w);
  if (RELU) {
    acc.x = fmaxf(acc.x, 0.f); acc.y = fmaxf(acc.y, 0.f);
    acc.z = fmaxf(acc.z, 0.f); acc.w = fmaxf(acc.w, 0.f);
  }
  ushort4 o;
  o.x = f2bf(acc.x); o.y = f2bf(acc.y); o.z = f2bf(acc.z); o.w = f2bf(acc.w);
  *(ushort4*)(out + (size_t)v * FDIM + lane * 4) = o;
}

// ---------------- fused mean-pool + classifier: one block per graph ----------------
// graph g's nodes are contiguous [gstart[g], gstart[g+1]); thread t owns channel t.
__global__ void pool_cls_kernel(const unsigned short* __restrict__ h2,
                                const int* __restrict__ gstart,
                                const float* __restrict__ Wc, const float* __restrict__ bcv,
                                float* __restrict__ out) {
  int g = blockIdx.x;
  int t = threadIdx.x;           // channel
  int lane = t & 63, w = t >> 6;
  int s = gstart[g], e = gstart[g + 1];
  float s0 = 0.f, s1 = 0.f, s2 = 0.f, s3 = 0.f;
  int n = s;
  for (; n + 4 <= e; n += 4) {
    s0 += b2f(h2[(size_t)(n + 0) * FDIM + t]);
    s1 += b2f(h2[(size_t)(n + 1) * FDIM + t]);
    s2 += b2f(h2[(size_t)(n + 2) * FDIM + t]);
    s3 += b2f(h2[(size_t)(n + 3) * FDIM + t]);
  }
  for (; n < e; ++n) s0 += b2f(h2[(size_t)n * FDIM + t]);
  float sum = (s0 + s1) + (s2 + s3);
  // per-thread partials for the 10 classes
  float p[NC];
  #pragma unroll
  for (int j = 0; j < NC; ++j) p[j] = sum * Wc[t * NC + j];
  #pragma unroll
  for (int j = 0; j < NC; ++j) {
    #pragma unroll
    for (int off = 1; off < 64; off <<= 1) p[j] += __shfl_xor(p[j], off);
  }
  __shared__ float wred[4][NC];
  if (lane == 0) {
    #pragma unroll
    for (int j = 0; j < NC; ++j) wred[w][j] = p[j];
  }
  __syncthreads();
  if (t < NC) {
    float inv = (e > s) ? (1.0f / (float)(e - s)) : 1.0f;
    float r = wred[0][t] + wred[1][t] + wred[2][t] + wred[3][t];
    out[g * NC + t] = r * inv + bcv[t];
  }
}

extern "C" void kernel_launch(void* const* d_in, const int* in_sizes, int n_in,
                              void* d_out, int out_size, void* d_ws, size_t ws_size,
                              hipStream_t stream) {
  const float* feat = (const float*)d_in[0];
  const int* src    = (const int*)d_in[1];
  const int* dst    = (const int*)d_in[2];
  const int* n2g    = (const int*)d_in[3];
  const float* W1  = (const float*)d_in[4];
  const float* al1 = (const float*)d_in[5];
  const float* ar1 = (const float*)d_in[6];
  const float* b1  = (const float*)d_in[7];
  const float* W2  = (const float*)d_in[8];
  const float* al2 = (const float*)d_in[9];
  const float* ar2 = (const float*)d_in[10];
  const float* b2  = (const float*)d_in[11];
  const float* Wc  = (const float*)d_in[12];
  const float* bc  = (const float*)d_in[13];
  float* out = (float*)d_out;

  char* wp = (char*)d_ws;
  auto carve = [&](size_t bytes) -> void* {
    void* p = (void*)wp;
    wp += (bytes + 255) & ~(size_t)255;
    return p;
  };
  unsigned char* fs = (unsigned char*)carve((size_t)MPAD * FDIM);        // 12.8 MB fp8 (padded)
  // h1/h2 share one bf16 buffer (h1 dead after gemm-2 consumes it)
  unsigned short* h1 = (unsigned short*)carve((size_t)MPAD * FDIM * 2);  // 25.6 MB bf16
  unsigned short* h2 = h1;
  unsigned short* Wt1 = (unsigned short*)carve((size_t)256 * 128 * 2);
  unsigned short* Wt2 = (unsigned short*)carve((size_t)256 * 256 * 2);
  float* el      = (float*)carve((size_t)MPAD * NHEAD * 4);
  float* er      = (float*)carve((size_t)MPAD * NHEAD * 4);
  int* rowstart  = (int*)  carve((size_t)(N_NODES + 1) * 4);
  int* esrc      = (int*)  carve((size_t)N_EDGES * 4);
  int* gstart    = (int*)  carve((size_t)(N_GRAPHS + 1) * 4);
  int* bsum      = (int*)  carve((size_t)SCAN_NB * 4);
  // zero-init region: cursor + cursor2 carved contiguously, single memset
  int* cursor    = (int*)  carve((size_t)N_NODES * 4);
  int* cursor2   = (int*)  carve((size_t)N_NODES * 4);
  size_t zlen = (size_t)((char*)(cursor2 + N_NODES) - (char*)cursor);
  (void)ws_size; (void)n_in; (void)in_sizes; (void)out_size;

  // CSR build + weight prep
  hipMemsetAsync(cursor, 0, zlen, stream);   // cursor, cursor2
  hist_cast_kernel<<<(N_EDGES + 255) / 256, 256, 0, stream>>>(dst, cursor, W1, W2, Wt1, Wt2, N_EDGES);
  scan_local_kernel<<<SCAN_NB, 256, 0, stream>>>(cursor, rowstart, bsum, N_NODES);
  scan_add_gb_kernel<<<(N_NODES + 255) / 256, 256, 0, stream>>>(rowstart, bsum, n2g, gstart, N_NODES);
  scatter_kernel<<<(N_EDGES + 255) / 256, 256, 0, stream>>>(src, dst, rowstart, cursor2, esrc, N_EDGES);

  // layer 1 (gemm stages fp32 feat directly; writes fs(fp8) + el + er)
  gemm_mfma<128, true><<<MPAD / 64, 256, 0, stream>>>(
      (const void*)feat, Wt1, fs, al1, ar1, el, er, N_NODES);
  edge_agg_kernel<true><<<(N_NODES * 64 + 255) / 256, 256, 0, stream>>>(
      rowstart, esrc, el, er, fs, b1, h1, N_NODES);

  // layer 2
  gemm_mfma<256, false><<<MPAD / 64, 256, 0, stream>>>(
      (const void*)h1, Wt2, fs, al2, ar2, el, er, N_NODES);
  edge_agg_kernel<false><<<(N_NODES * 64 + 255) / 256, 256, 0, stream>>>(
      rowstart, esrc, el, er, fs, b2, h2, N_NODES);

  // readout: fused mean-pool + classifier (graph nodes contiguous)
  pool_cls_kernel<<<N_GRAPHS, 256, 0, stream>>>(h2, gstart, Wc, bc, out);
}

// Round 16
// 313.150 us; speedup vs baseline: 1.0135x; 1.0135x over previous
//
#include <hip/hip_runtime.h>
#include <hip/hip_bf16.h>

#define N_NODES 50000
#define N_EDGES 500000
#define N_GRAPHS 64
#define FDIM 256   // H*HID
#define NHEAD 8
#define NC 10
#define SLOPE 0.2f
#define MPAD 50048  // N_NODES rounded up to 64
#define SCAN_NB ((N_NODES + 1023) / 1024)   // 49 blocks of 1024 elements

typedef __attribute__((ext_vector_type(8))) short bf16x8;
typedef __attribute__((ext_vector_type(4))) float f32x4;
typedef __attribute__((ext_vector_type(2))) float f32x2;

__device__ __forceinline__ unsigned short f2bf(float f) {
  unsigned x = __float_as_uint(f);
  x += 0x7fff + ((x >> 16) & 1);   // RNE
  return (unsigned short)(x >> 16);
}
__device__ __forceinline__ float b2f(unsigned short u) {
  return __uint_as_float((unsigned)u << 16);
}

// ---------------- CSR build: histogram + fused weight transposes ----------------
__global__ void hist_cast_kernel(const int* __restrict__ dst, int* __restrict__ deg,
                                 const float* __restrict__ W1, const float* __restrict__ W2,
                                 unsigned short* __restrict__ Wt1, unsigned short* __restrict__ Wt2,
                                 int E) {
  int e = blockIdx.x * blockDim.x + threadIdx.x;
  if (e < E) atomicAdd(&deg[dst[e]], 1);
  // first 98304 threads also do the weight transposes (independent work)
  if (e < 256 * 128) {
    int n = e / 128, k = e % 128;
    Wt1[(size_t)n * 128 + k] = f2bf(W1[(size_t)k * 256 + n]);
  } else if (e < 256 * 128 + 256 * 256) {
    int t2 = e - 256 * 128;
    int n = t2 / 256, k = t2 % 256;
    Wt2[(size_t)n * 256 + k] = f2bf(W2[(size_t)k * 256 + n]);
  }
}

// ---- multi-block exclusive scan of deg[0..n) -> rowstart[0..n] ----
__global__ void scan_local_kernel(const int* __restrict__ deg, int* __restrict__ rowstart,
                                  int* __restrict__ bsum, int n) {
  __shared__ int ws[4];
  int t = threadIdx.x, lane = t & 63, w = t >> 6;
  int base = blockIdx.x * 1024 + t * 4;
  int4 v = make_int4(0, 0, 0, 0);
  if (base + 3 < n) {
    v = *(const int4*)(deg + base);
  } else {
    if (base + 0 < n) v.x = deg[base + 0];
    if (base + 1 < n) v.y = deg[base + 1];
    if (base + 2 < n) v.z = deg[base + 2];
    if (base + 3 < n) v.w = deg[base + 3];
  }
  int s = v.x + v.y + v.z + v.w;
  int x = s;
  #pragma unroll
  for (int off = 1; off < 64; off <<= 1) {
    int y = __shfl_up(x, off);
    if (lane >= off) x += y;
  }
  if (lane == 63) ws[w] = x;
  __syncthreads();
  int woff = 0;
  #pragma unroll
  for (int i = 0; i < 4; ++i) woff += (i < w) ? ws[i] : 0;
  int excl = woff + x - s;
  int4 o;
  o.x = excl;
  o.y = excl + v.x;
  o.z = excl + v.x + v.y;
  o.w = excl + v.x + v.y + v.z;
  if (base + 3 < n) {
    *(int4*)(rowstart + base) = o;
  } else {
    if (base + 0 < n) rowstart[base + 0] = o.x;
    if (base + 1 < n) rowstart[base + 1] = o.y;
    if (base + 2 < n) rowstart[base + 2] = o.z;
    if (base + 3 < n) rowstart[base + 3] = o.w;
  }
  if (t == 255) bsum[blockIdx.x] = woff + x;
}

// phase 2+3 + graph_bounds fused: each block wave-scans the 49 block sums,
// adds offsets, fills gstart. rowstart[n]=E.
__global__ void scan_add_gb_kernel(int* __restrict__ rowstart, const int* __restrict__ bsum,
                                   const int* __restrict__ n2g, int* __restrict__ gstart, int n) {
  __shared__ int boff[64];
  int t = threadIdx.x;
  if (t < 64) {
    int v = (t < SCAN_NB) ? bsum[t] : 0;
    int x = v;
    #pragma unroll
    for (int off = 1; off < 64; off <<= 1) {
      int y = __shfl_up(x, off);
      if (t >= off) x += y;
    }
    boff[t] = x - v;   // exclusive prefix
  }
  __syncthreads();
  int i = blockIdx.x * blockDim.x + threadIdx.x;
  if (i < n) {
    rowstart[i] += boff[i >> 10];
    int g1 = n2g[i];
    int g0 = (i == 0) ? -1 : n2g[i - 1];
    for (int g = g0 + 1; g <= g1; ++g) gstart[g] = i;
    if (i == n - 1) {
      for (int g = g1 + 1; g <= N_GRAPHS; ++g) gstart[g] = n;
    }
  }
  if (i == 0) rowstart[n] = N_EDGES;
}

__global__ void scatter_kernel(const int* __restrict__ src, const int* __restrict__ dst,
                               const int* __restrict__ rowstart, int* __restrict__ cursor,
                               int* __restrict__ esrc, int E) {
  int e = blockIdx.x * blockDim.x + threadIdx.x;
  if (e >= E) return;
  int d = dst[e];
  int p = atomicAdd(&cursor[d], 1);
  esrc[rowstart[d] + p] = src[e];
}

// ---------------- LDS-staged MFMA GEMM + fused attention logits ----------------
// fs output FP8 e4m3 (HW packed): 12.8 MB -> 3x better L2 coverage for the
// edge gather. el/er computed from fp32 acc (alpha weights unaffected).
template<int K, bool AF32>
__global__ void gemm_mfma(const void* __restrict__ Avoid,
                          const unsigned short* __restrict__ Wt,
                          unsigned char* __restrict__ fs,
                          const float* __restrict__ al, const float* __restrict__ ar,
                          float* __restrict__ el, float* __restrict__ er, int nrows) {
  constexpr int KC = K / 32;
  __shared__ __align__(16) unsigned short Albs[64 * 32];    // [row][32k] 4 KB
  __shared__ __align__(16) unsigned short Wlds[256 * 32];   // [n][32k] 16 KB
  const float* Af = (const float*)Avoid;
  const unsigned short* Ab = (const unsigned short*)Avoid;
  int t = threadIdx.x;
  int lane = t & 63;
  int w = t >> 6;
  int row0 = blockIdx.x * 64;
  int m = lane & 15;
  int q = lane >> 4;
  float4 a32[2];
  bf16x8 a16;
  bf16x8 wtr[4];
  int arow = t >> 2, apiece = t & 3;
  int agrow = min(row0 + arow, nrows - 1);
  int frow0 = t >> 3, fquad0 = t & 7;
  int frow1 = (256 + t) >> 3, fquad1 = t & 7;
  int fgrow0 = min(row0 + frow0, nrows - 1);
  int fgrow1 = min(row0 + frow1, nrows - 1);

  auto stage = [&](int kc) {
    if (AF32) {
      a32[0] = *(const float4*)(Af + (size_t)fgrow0 * K + kc * 32 + fquad0 * 4);
      a32[1] = *(const float4*)(Af + (size_t)fgrow1 * K + kc * 32 + fquad1 * 4);
    } else {
      a16 = *(const bf16x8*)(Ab + (size_t)agrow * K + kc * 32 + apiece * 8);
    }
    #pragma unroll
    for (int j = 0; j < 4; ++j) {
      int row = j * 64 + (t >> 2);
      wtr[j] = *(const bf16x8*)(Wt + (size_t)row * K + kc * 32 + (t & 3) * 8);
    }
  };
  auto commit = [&]() {
    if (AF32) {
      ushort4 o0, o1;
      o0.x = f2bf(a32[0].x); o0.y = f2bf(a32[0].y); o0.z = f2bf(a32[0].z); o0.w = f2bf(a32[0].w);
      o1.x = f2bf(a32[1].x); o1.y = f2bf(a32[1].y); o1.z = f2bf(a32[1].z); o1.w = f2bf(a32[1].w);
      *(ushort4*)(Albs + frow0 * 32 + fquad0 * 4) = o0;
      *(ushort4*)(Albs + frow1 * 32 + fquad1 * 4) = o1;
    } else {
      *(bf16x8*)(Albs + arow * 32 + apiece * 8) = a16;
    }
    #pragma unroll
    for (int j = 0; j < 4; ++j) {
      int row = j * 64 + (t >> 2);
      *(bf16x8*)(Wlds + row * 32 + (t & 3) * 8) = wtr[j];
    }
  };

  f32x4 acc[16];
  #pragma unroll
  for (int nt = 0; nt < 16; ++nt) acc[nt] = (f32x4){0.f, 0.f, 0.f, 0.f};

  stage(0);
  commit();
  for (int kc = 0; kc < KC; ++kc) {
    __syncthreads();
    if (kc + 1 < KC) stage(kc + 1);
    bf16x8 af = *(const bf16x8*)(Albs + (w * 16 + m) * 32 + q * 8);
    #pragma unroll
    for (int nt = 0; nt < 16; ++nt) {
      bf16x8 bfv = *(const bf16x8*)(Wlds + (nt * 16 + m) * 32 + q * 8);
      acc[nt] = __builtin_amdgcn_mfma_f32_16x16x32_bf16(bfv, af, acc[nt], 0, 0, 0);
    }
    __syncthreads();
    if (kc + 1 < KC) commit();
  }

  int node = row0 + w * 16 + m;
  float elh[NHEAD], erh[NHEAD];
  #pragma unroll
  for (int h = 0; h < NHEAD; ++h) { elh[h] = 0.f; erh[h] = 0.f; }
  #pragma unroll
  for (int nt = 0; nt < 16; ++nt) {
    int h = nt >> 1;
    int c0 = (nt & 1) * 16 + q * 4;
    float4 a4 = *(const float4*)(al + h * 32 + c0);
    float4 r4 = *(const float4*)(ar + h * 32 + c0);
    elh[h] += acc[nt][0] * a4.x + acc[nt][1] * a4.y + acc[nt][2] * a4.z + acc[nt][3] * a4.w;
    erh[h] += acc[nt][0] * r4.x + acc[nt][1] * r4.y + acc[nt][2] * r4.z + acc[nt][3] * r4.w;
  }
  #pragma unroll
  for (int h = 0; h < NHEAD; ++h) {
    elh[h] += __shfl_xor(elh[h], 16); elh[h] += __shfl_xor(elh[h], 32);
    erh[h] += __shfl_xor(erh[h], 16); erh[h] += __shfl_xor(erh[h], 32);
  }
  // fs store: pack 4 fp32 -> 4 fp8 bytes (one dword per nt)
  #pragma unroll
  for (int nt = 0; nt < 16; ++nt) {
    int pk = 0;
    pk = __builtin_amdgcn_cvt_pk_fp8_f32(acc[nt][0], acc[nt][1], pk, false);
    pk = __builtin_amdgcn_cvt_pk_fp8_f32(acc[nt][2], acc[nt][3], pk, true);
    *(unsigned*)(fs + (size_t)node * 256 + nt * 16 + q * 4) = (unsigned)pk;
  }
  *(float2*)(el + (size_t)node * NHEAD + 2 * q) = make_float2(elh[2 * q], elh[2 * q + 1]);
  *(float2*)(er + (size_t)node * NHEAD + 2 * q) = make_float2(erh[2 * q], erh[2 * q + 1]);
}

// ---------------- fused edge softmax + aggregation: one wave per dst node ----------------
// Lane-specialized weights; dual accumulators; fs gather in FP8.
template<bool RELU>
__global__ __launch_bounds__(256, 8)
void edge_agg_kernel(const int* __restrict__ rowstart, const int* __restrict__ esrc,
                     const float* __restrict__ el, const float* __restrict__ er,
                     const unsigned char* __restrict__ fs,
                     const float* __restrict__ bias,
                     unsigned short* __restrict__ out, int nnodes) {
  int gid = blockIdx.x * blockDim.x + threadIdx.x;
  int v = gid >> 6;
  int lane = threadIdx.x & 63;
  if (v >= nnodes) return;
  int h = lane >> 3;       // consumer head
  int t8 = lane >> 3;      // producer edge slot
  int hh = lane & 7;       // producer head
  int row0 = rowstart[v];
  int deg = rowstart[v + 1] - row0;
  float er_w = er[v * NHEAD + hh];
  const unsigned char* fsl = fs + lane * 4;   // 4 fp8 bytes per lane
  const float* elp = el;
  float4 acc0 = make_float4(0.f, 0.f, 0.f, 0.f);
  float4 acc1 = make_float4(0.f, 0.f, 0.f, 0.f);
  float ws0 = 0.f, ws1 = 0.f;
  for (int base = 0; base < deg; base += 64) {
    int mm = min(deg - base, 64);
    int li = (lane < mm) ? lane : (mm - 1);
    int es = esrc[row0 + base + li];
    for (int j0 = 0; j0 < mm; j0 += 8) {
      int sj = __shfl(es, min(j0 + t8, mm - 1));
      float x = elp[(unsigned)sj * 8u + hh] + er_w;
      x = fmaxf(x, SLOPE * x);
      float wp = __expf(x);
      if (j0 + t8 >= mm) wp = 0.f;
      float wt[8]; unsigned f[8];
      #pragma unroll
      for (int t = 0; t < 8; ++t) wt[t] = __shfl(wp, t * 8 + h);
      #pragma unroll
      for (int t = 0; t < 8; ++t) {
        int s = __shfl(es, min(j0 + t, mm - 1));
        f[t] = *(const unsigned*)(fsl + ((unsigned)s << 8));   // 256 B row stride
      }
      #pragma unroll
      for (int t = 0; t < 8; ++t) {
        float wgt = wt[t];
        f32x2 lo = __builtin_amdgcn_cvt_pk_f32_fp8(f[t], false);
        f32x2 hi = __builtin_amdgcn_cvt_pk_f32_fp8(f[t], true);
        if (t & 1) {
          ws1 += wgt;
          acc1.x = fmaf(wgt, lo.x, acc1.x);
          acc1.y = fmaf(wgt, lo.y, acc1.y);
          acc1.z = fmaf(wgt, hi.x, acc1.z);
          acc1.w = fmaf(wgt, hi.y, acc1.w);
        } else {
          ws0 += wgt;
          acc0.x = fmaf(wgt, lo.x, acc0.x);
          acc0.y = fmaf(wgt, lo.y, acc0.y);
          acc0.z = fmaf(wgt, hi.x, acc0.z);
          acc0.w = fmaf(wgt, hi.y, acc0.w);
        }
      }
    }
  }
  float wsum = ws0 + ws1;
  float4 acc;
  acc.x = acc0.x + acc1.x; acc.y = acc0.y + acc1.y;
  acc.z = acc0.z + acc1.z; acc.w = acc0.w + acc1.w;
  float rdenom = (deg > 0) ? (1.0f / wsum) : 0.f;
  const float4 b = *(const float4*)(bias + lane * 4);
  acc.x = fmaf(acc.x, rdenom, b.x);
  acc.y = fmaf(acc.y, rdenom, b.y);
  acc.z = fmaf(acc.z, rdenom, b.z);
  acc.w = fmaf(acc.w, rdenom, b.w);
  if (RELU) {
    acc.x = fmaxf(acc.x, 0.f); acc.y = fmaxf(acc.y, 0.f);
    acc.z = fmaxf(acc.z, 0.f); acc.w = fmaxf(acc.w, 0.f);
  }
  ushort4 o;
  o.x = f2bf(acc.x); o.y = f2bf(acc.y); o.z = f2bf(acc.z); o.w = f2bf(acc.w);
  *(ushort4*)(out + (size_t)v * FDIM + lane * 4) = o;
}

// ---------------- per-graph sum pool (bf16 input, wave per 8-node chunk) ----------------
__global__ void pool_sum_kernel(const unsigned short* __restrict__ h2, const int* __restrict__ n2g,
                                float* __restrict__ hg, int nnodes) {
  int wave = (blockIdx.x * blockDim.x + threadIdx.x) >> 6;
  int lane = threadIdx.x & 63;
  int n0 = wave * 8;
  if (n0 >= nnodes) return;
  int n1 = min(n0 + 8, nnodes);
  int curg = n2g[n0];
  float4 acc = make_float4(0.f, 0.f, 0.f, 0.f);
  for (int n = n0; n < n1; ++n) {
    int g = n2g[n];
    if (g != curg) {
      float* p = &hg[(size_t)curg * FDIM + lane * 4];
      atomicAdd(p + 0, acc.x); atomicAdd(p + 1, acc.y);
      atomicAdd(p + 2, acc.z); atomicAdd(p + 3, acc.w);
      acc = make_float4(0.f, 0.f, 0.f, 0.f);
      curg = g;
    }
    ushort4 u = *(const ushort4*)&h2[(size_t)n * FDIM + lane * 4];
    acc.x += b2f(u.x); acc.y += b2f(u.y); acc.z += b2f(u.z); acc.w += b2f(u.w);
  }
  float* p = &hg[(size_t)curg * FDIM + lane * 4];
  atomicAdd(p + 0, acc.x); atomicAdd(p + 1, acc.y);
  atomicAdd(p + 2, acc.z); atomicAdd(p + 3, acc.w);
}

// ---------------- classifier (divides pooled sums by per-graph count) ----------------
__global__ void classifier_kernel(const float* __restrict__ hgsum, const int* __restrict__ gstart,
                                  const float* __restrict__ Wc, const float* __restrict__ bcv,
                                  float* __restrict__ out) {
  int tid = blockIdx.x * blockDim.x + threadIdx.x;
  if (tid >= N_GRAPHS * NC) return;
  int b = tid / NC, j = tid % NC;
  int cnt = gstart[b + 1] - gstart[b];
  float inv = (cnt > 0) ? (1.0f / (float)cnt) : 1.0f;
  float s = 0.f;
  for (int c = 0; c < FDIM; ++c) s += hgsum[b * FDIM + c] * Wc[c * NC + j];
  out[tid] = s * inv + bcv[j];
}

extern "C" void kernel_launch(void* const* d_in, const int* in_sizes, int n_in,
                              void* d_out, int out_size, void* d_ws, size_t ws_size,
                              hipStream_t stream) {
  const float* feat = (const float*)d_in[0];
  const int* src    = (const int*)d_in[1];
  const int* dst    = (const int*)d_in[2];
  const int* n2g    = (const int*)d_in[3];
  const float* W1  = (const float*)d_in[4];
  const float* al1 = (const float*)d_in[5];
  const float* ar1 = (const float*)d_in[6];
  const float* b1  = (const float*)d_in[7];
  const float* W2  = (const float*)d_in[8];
  const float* al2 = (const float*)d_in[9];
  const float* ar2 = (const float*)d_in[10];
  const float* b2  = (const float*)d_in[11];
  const float* Wc  = (const float*)d_in[12];
  const float* bc  = (const float*)d_in[13];
  float* out = (float*)d_out;

  char* wp = (char*)d_ws;
  auto carve = [&](size_t bytes) -> void* {
    void* p = (void*)wp;
    wp += (bytes + 255) & ~(size_t)255;
    return p;
  };
  unsigned char* fs = (unsigned char*)carve((size_t)MPAD * FDIM);        // 12.8 MB fp8 (padded)
  // h1/h2 share one bf16 buffer (h1 dead after gemm-2 consumes it)
  unsigned short* h1 = (unsigned short*)carve((size_t)MPAD * FDIM * 2);  // 25.6 MB bf16
  unsigned short* h2 = h1;
  unsigned short* Wt1 = (unsigned short*)carve((size_t)256 * 128 * 2);
  unsigned short* Wt2 = (unsigned short*)carve((size_t)256 * 256 * 2);
  float* el      = (float*)carve((size_t)MPAD * NHEAD * 4);
  float* er      = (float*)carve((size_t)MPAD * NHEAD * 4);
  int* rowstart  = (int*)  carve((size_t)(N_NODES + 1) * 4);
  int* esrc      = (int*)  carve((size_t)N_EDGES * 4);
  int* gstart    = (int*)  carve((size_t)(N_GRAPHS + 1) * 4);
  int* bsum      = (int*)  carve((size_t)SCAN_NB * 4);
  // zero-init region: cursor + cursor2 + hg carved contiguously, single memset
  int* cursor    = (int*)  carve((size_t)N_NODES * 4);
  int* cursor2   = (int*)  carve((size_t)N_NODES * 4);
  float* hg      = (float*)carve((size_t)N_GRAPHS * FDIM * 4);
  size_t zlen = (size_t)((char*)(hg + N_GRAPHS * FDIM) - (char*)cursor);
  (void)ws_size; (void)n_in; (void)in_sizes; (void)out_size;

  // CSR build + weight prep
  hipMemsetAsync(cursor, 0, zlen, stream);   // cursor, cursor2, hg
  hist_cast_kernel<<<(N_EDGES + 255) / 256, 256, 0, stream>>>(dst, cursor, W1, W2, Wt1, Wt2, N_EDGES);
  scan_local_kernel<<<SCAN_NB, 256, 0, stream>>>(cursor, rowstart, bsum, N_NODES);
  scan_add_gb_kernel<<<(N_NODES + 255) / 256, 256, 0, stream>>>(rowstart, bsum, n2g, gstart, N_NODES);
  scatter_kernel<<<(N_EDGES + 255) / 256, 256, 0, stream>>>(src, dst, rowstart, cursor2, esrc, N_EDGES);

  // layer 1 (gemm stages fp32 feat directly; writes fs(fp8) + el + er)
  gemm_mfma<128, true><<<MPAD / 64, 256, 0, stream>>>(
      (const void*)feat, Wt1, fs, al1, ar1, el, er, N_NODES);
  edge_agg_kernel<true><<<(N_NODES * 64 + 255) / 256, 256, 0, stream>>>(
      rowstart, esrc, el, er, fs, b1, h1, N_NODES);

  // layer 2
  gemm_mfma<256, false><<<MPAD / 64, 256, 0, stream>>>(
      (const void*)h1, Wt2, fs, al2, ar2, el, er, N_NODES);
  edge_agg_kernel<false><<<(N_NODES * 64 + 255) / 256, 256, 0, stream>>>(
      rowstart, esrc, el, er, fs, b2, h2, N_NODES);

  // readout (R14 proven shape: node-parallel pool + tiny classifier)
  {
    int waves = (N_NODES + 7) / 8;
    pool_sum_kernel<<<(waves * 64 + 255) / 256, 256, 0, stream>>>(h2, n2g, hg, N_NODES);
  }
  classifier_kernel<<<(N_GRAPHS * NC + 255) / 256, 256, 0, stream>>>(hg, gstart, Wc, bc, out);
}

// Round 17
// 282.570 us; speedup vs baseline: 1.1232x; 1.1082x over previous
//
#include <hip/hip_runtime.h>
#include <hip/hip_bf16.h>

#define N_NODES 50000
#define N_EDGES 500000
#define N_GRAPHS 64
#define FDIM 256   // H*HID
#define NHEAD 8
#define NC 10
#define SLOPE 0.2f
#define MPAD 50048  // N_NODES rounded up to 64
#define SCAN_NB ((N_NODES + 1023) / 1024)   // 49 blocks of 1024 elements
#define POOL_NB 512
#define POOL_PER ((N_NODES + POOL_NB - 1) / POOL_NB)   // 98 nodes per block

typedef __attribute__((ext_vector_type(8))) short bf16x8;
typedef __attribute__((ext_vector_type(4))) float f32x4;
typedef __attribute__((ext_vector_type(2))) float f32x2;

__device__ __forceinline__ unsigned short f2bf(float f) {
  unsigned x = __float_as_uint(f);
  x += 0x7fff + ((x >> 16) & 1);   // RNE
  return (unsigned short)(x >> 16);
}
__device__ __forceinline__ float b2f(unsigned short u) {
  return __uint_as_float((unsigned)u << 16);
}

// ---------------- CSR build: histogram + fused weight transposes ----------------
__global__ void hist_cast_kernel(const int* __restrict__ dst, int* __restrict__ deg,
                                 const float* __restrict__ W1, const float* __restrict__ W2,
                                 unsigned short* __restrict__ Wt1, unsigned short* __restrict__ Wt2,
                                 int E) {
  int e = blockIdx.x * blockDim.x + threadIdx.x;
  if (e < E) atomicAdd(&deg[dst[e]], 1);
  // first 98304 threads also do the weight transposes (independent work)
  if (e < 256 * 128) {
    int n = e / 128, k = e % 128;
    Wt1[(size_t)n * 128 + k] = f2bf(W1[(size_t)k * 256 + n]);
  } else if (e < 256 * 128 + 256 * 256) {
    int t2 = e - 256 * 128;
    int n = t2 / 256, k = t2 % 256;
    Wt2[(size_t)n * 256 + k] = f2bf(W2[(size_t)k * 256 + n]);
  }
}

// ---- multi-block exclusive scan of deg[0..n) -> rowstart[0..n] ----
__global__ void scan_local_kernel(const int* __restrict__ deg, int* __restrict__ rowstart,
                                  int* __restrict__ bsum, int n) {
  __shared__ int ws[4];
  int t = threadIdx.x, lane = t & 63, w = t >> 6;
  int base = blockIdx.x * 1024 + t * 4;
  int4 v = make_int4(0, 0, 0, 0);
  if (base + 3 < n) {
    v = *(const int4*)(deg + base);
  } else {
    if (base + 0 < n) v.x = deg[base + 0];
    if (base + 1 < n) v.y = deg[base + 1];
    if (base + 2 < n) v.z = deg[base + 2];
    if (base + 3 < n) v.w = deg[base + 3];
  }
  int s = v.x + v.y + v.z + v.w;
  int x = s;
  #pragma unroll
  for (int off = 1; off < 64; off <<= 1) {
    int y = __shfl_up(x, off);
    if (lane >= off) x += y;
  }
  if (lane == 63) ws[w] = x;
  __syncthreads();
  int woff = 0;
  #pragma unroll
  for (int i = 0; i < 4; ++i) woff += (i < w) ? ws[i] : 0;
  int excl = woff + x - s;
  int4 o;
  o.x = excl;
  o.y = excl + v.x;
  o.z = excl + v.x + v.y;
  o.w = excl + v.x + v.y + v.z;
  if (base + 3 < n) {
    *(int4*)(rowstart + base) = o;
  } else {
    if (base + 0 < n) rowstart[base + 0] = o.x;
    if (base + 1 < n) rowstart[base + 1] = o.y;
    if (base + 2 < n) rowstart[base + 2] = o.z;
    if (base + 3 < n) rowstart[base + 3] = o.w;
  }
  if (t == 255) bsum[blockIdx.x] = woff + x;
}

// phase 2+3 + graph_bounds fused: each block wave-scans the 49 block sums,
// adds offsets, fills gstart. rowstart[n]=E.
__global__ void scan_add_gb_kernel(int* __restrict__ rowstart, const int* __restrict__ bsum,
                                   const int* __restrict__ n2g, int* __restrict__ gstart, int n) {
  __shared__ int boff[64];
  int t = threadIdx.x;
  if (t < 64) {
    int v = (t < SCAN_NB) ? bsum[t] : 0;
    int x = v;
    #pragma unroll
    for (int off = 1; off < 64; off <<= 1) {
      int y = __shfl_up(x, off);
      if (t >= off) x += y;
    }
    boff[t] = x - v;   // exclusive prefix
  }
  __syncthreads();
  int i = blockIdx.x * blockDim.x + threadIdx.x;
  if (i < n) {
    rowstart[i] += boff[i >> 10];
    int g1 = n2g[i];
    int g0 = (i == 0) ? -1 : n2g[i - 1];
    for (int g = g0 + 1; g <= g1; ++g) gstart[g] = i;
    if (i == n - 1) {
      for (int g = g1 + 1; g <= N_GRAPHS; ++g) gstart[g] = n;
    }
  }
  if (i == 0) rowstart[n] = N_EDGES;
}

__global__ void scatter_kernel(const int* __restrict__ src, const int* __restrict__ dst,
                               const int* __restrict__ rowstart, int* __restrict__ cursor,
                               int* __restrict__ esrc, int E) {
  int e = blockIdx.x * blockDim.x + threadIdx.x;
  if (e >= E) return;
  int d = dst[e];
  int p = atomicAdd(&cursor[d], 1);
  esrc[rowstart[d] + p] = src[e];
}

// ---------------- LDS-staged MFMA GEMM + fused attention logits ----------------
// fs output FP8 e4m3 (HW packed): 12.8 MB -> 3x better L2 coverage for the
// edge gather. el/er computed from fp32 acc (alpha weights unaffected).
template<int K, bool AF32>
__global__ void gemm_mfma(const void* __restrict__ Avoid,
                          const unsigned short* __restrict__ Wt,
                          unsigned char* __restrict__ fs,
                          const float* __restrict__ al, const float* __restrict__ ar,
                          float* __restrict__ el, float* __restrict__ er, int nrows) {
  constexpr int KC = K / 32;
  __shared__ __align__(16) unsigned short Albs[64 * 32];    // [row][32k] 4 KB
  __shared__ __align__(16) unsigned short Wlds[256 * 32];   // [n][32k] 16 KB
  const float* Af = (const float*)Avoid;
  const unsigned short* Ab = (const unsigned short*)Avoid;
  int t = threadIdx.x;
  int lane = t & 63;
  int w = t >> 6;
  int row0 = blockIdx.x * 64;
  int m = lane & 15;
  int q = lane >> 4;
  float4 a32[2];
  bf16x8 a16;
  bf16x8 wtr[4];
  int arow = t >> 2, apiece = t & 3;
  int agrow = min(row0 + arow, nrows - 1);
  int frow0 = t >> 3, fquad0 = t & 7;
  int frow1 = (256 + t) >> 3, fquad1 = t & 7;
  int fgrow0 = min(row0 + frow0, nrows - 1);
  int fgrow1 = min(row0 + frow1, nrows - 1);

  auto stage = [&](int kc) {
    if (AF32) {
      a32[0] = *(const float4*)(Af + (size_t)fgrow0 * K + kc * 32 + fquad0 * 4);
      a32[1] = *(const float4*)(Af + (size_t)fgrow1 * K + kc * 32 + fquad1 * 4);
    } else {
      a16 = *(const bf16x8*)(Ab + (size_t)agrow * K + kc * 32 + apiece * 8);
    }
    #pragma unroll
    for (int j = 0; j < 4; ++j) {
      int row = j * 64 + (t >> 2);
      wtr[j] = *(const bf16x8*)(Wt + (size_t)row * K + kc * 32 + (t & 3) * 8);
    }
  };
  auto commit = [&]() {
    if (AF32) {
      ushort4 o0, o1;
      o0.x = f2bf(a32[0].x); o0.y = f2bf(a32[0].y); o0.z = f2bf(a32[0].z); o0.w = f2bf(a32[0].w);
      o1.x = f2bf(a32[1].x); o1.y = f2bf(a32[1].y); o1.z = f2bf(a32[1].z); o1.w = f2bf(a32[1].w);
      *(ushort4*)(Albs + frow0 * 32 + fquad0 * 4) = o0;
      *(ushort4*)(Albs + frow1 * 32 + fquad1 * 4) = o1;
    } else {
      *(bf16x8*)(Albs + arow * 32 + apiece * 8) = a16;
    }
    #pragma unroll
    for (int j = 0; j < 4; ++j) {
      int row = j * 64 + (t >> 2);
      *(bf16x8*)(Wlds + row * 32 + (t & 3) * 8) = wtr[j];
    }
  };

  f32x4 acc[16];
  #pragma unroll
  for (int nt = 0; nt < 16; ++nt) acc[nt] = (f32x4){0.f, 0.f, 0.f, 0.f};

  stage(0);
  commit();
  for (int kc = 0; kc < KC; ++kc) {
    __syncthreads();
    if (kc + 1 < KC) stage(kc + 1);
    bf16x8 af = *(const bf16x8*)(Albs + (w * 16 + m) * 32 + q * 8);
    #pragma unroll
    for (int nt = 0; nt < 16; ++nt) {
      bf16x8 bfv = *(const bf16x8*)(Wlds + (nt * 16 + m) * 32 + q * 8);
      acc[nt] = __builtin_amdgcn_mfma_f32_16x16x32_bf16(bfv, af, acc[nt], 0, 0, 0);
    }
    __syncthreads();
    if (kc + 1 < KC) commit();
  }

  int node = row0 + w * 16 + m;
  float elh[NHEAD], erh[NHEAD];
  #pragma unroll
  for (int h = 0; h < NHEAD; ++h) { elh[h] = 0.f; erh[h] = 0.f; }
  #pragma unroll
  for (int nt = 0; nt < 16; ++nt) {
    int h = nt >> 1;
    int c0 = (nt & 1) * 16 + q * 4;
    float4 a4 = *(const float4*)(al + h * 32 + c0);
    float4 r4 = *(const float4*)(ar + h * 32 + c0);
    elh[h] += acc[nt][0] * a4.x + acc[nt][1] * a4.y + acc[nt][2] * a4.z + acc[nt][3] * a4.w;
    erh[h] += acc[nt][0] * r4.x + acc[nt][1] * r4.y + acc[nt][2] * r4.z + acc[nt][3] * r4.w;
  }
  #pragma unroll
  for (int h = 0; h < NHEAD; ++h) {
    elh[h] += __shfl_xor(elh[h], 16); elh[h] += __shfl_xor(elh[h], 32);
    erh[h] += __shfl_xor(erh[h], 16); erh[h] += __shfl_xor(erh[h], 32);
  }
  // fs store: pack 4 fp32 -> 4 fp8 bytes (one dword per nt)
  #pragma unroll
  for (int nt = 0; nt < 16; ++nt) {
    int pk = 0;
    pk = __builtin_amdgcn_cvt_pk_fp8_f32(acc[nt][0], acc[nt][1], pk, false);
    pk = __builtin_amdgcn_cvt_pk_fp8_f32(acc[nt][2], acc[nt][3], pk, true);
    *(unsigned*)(fs + (size_t)node * 256 + nt * 16 + q * 4) = (unsigned)pk;
  }
  *(float2*)(el + (size_t)node * NHEAD + 2 * q) = make_float2(elh[2 * q], elh[2 * q + 1]);
  *(float2*)(er + (size_t)node * NHEAD + 2 * q) = make_float2(erh[2 * q], erh[2 * q + 1]);
}

// ---------------- fused edge softmax + aggregation: one wave per dst node ----------------
// Lane-specialized weights; dual accumulators; fs gather in FP8.
template<bool RELU>
__global__ __launch_bounds__(256, 8)
void edge_agg_kernel(const int* __restrict__ rowstart, const int* __restrict__ esrc,
                     const float* __restrict__ el, const float* __restrict__ er,
                     const unsigned char* __restrict__ fs,
                     const float* __restrict__ bias,
                     unsigned short* __restrict__ out, int nnodes) {
  int gid = blockIdx.x * blockDim.x + threadIdx.x;
  int v = gid >> 6;
  int lane = threadIdx.x & 63;
  if (v >= nnodes) return;
  int h = lane >> 3;       // consumer head
  int t8 = lane >> 3;      // producer edge slot
  int hh = lane & 7;       // producer head
  int row0 = rowstart[v];
  int deg = rowstart[v + 1] - row0;
  float er_w = er[v * NHEAD + hh];
  const unsigned char* fsl = fs + lane * 4;   // 4 fp8 bytes per lane
  const float* elp = el;
  float4 acc0 = make_float4(0.f, 0.f, 0.f, 0.f);
  float4 acc1 = make_float4(0.f, 0.f, 0.f, 0.f);
  float ws0 = 0.f, ws1 = 0.f;
  for (int base = 0; base < deg; base += 64) {
    int mm = min(deg - base, 64);
    int li = (lane < mm) ? lane : (mm - 1);
    int es = esrc[row0 + base + li];
    for (int j0 = 0; j0 < mm; j0 += 8) {
      int sj = __shfl(es, min(j0 + t8, mm - 1));
      float x = elp[(unsigned)sj * 8u + hh] + er_w;
      x = fmaxf(x, SLOPE * x);
      float wp = __expf(x);
      if (j0 + t8 >= mm) wp = 0.f;
      float wt[8]; unsigned f[8];
      #pragma unroll
      for (int t = 0; t < 8; ++t) wt[t] = __shfl(wp, t * 8 + h);
      #pragma unroll
      for (int t = 0; t < 8; ++t) {
        int s = __shfl(es, min(j0 + t, mm - 1));
        f[t] = *(const unsigned*)(fsl + ((unsigned)s << 8));   // 256 B row stride
      }
      #pragma unroll
      for (int t = 0; t < 8; ++t) {
        float wgt = wt[t];
        f32x2 lo = __builtin_amdgcn_cvt_pk_f32_fp8(f[t], false);
        f32x2 hi = __builtin_amdgcn_cvt_pk_f32_fp8(f[t], true);
        if (t & 1) {
          ws1 += wgt;
          acc1.x = fmaf(wgt, lo.x, acc1.x);
          acc1.y = fmaf(wgt, lo.y, acc1.y);
          acc1.z = fmaf(wgt, hi.x, acc1.z);
          acc1.w = fmaf(wgt, hi.y, acc1.w);
        } else {
          ws0 += wgt;
          acc0.x = fmaf(wgt, lo.x, acc0.x);
          acc0.y = fmaf(wgt, lo.y, acc0.y);
          acc0.z = fmaf(wgt, hi.x, acc0.z);
          acc0.w = fmaf(wgt, hi.y, acc0.w);
        }
      }
    }
  }
  float wsum = ws0 + ws1;
  float4 acc;
  acc.x = acc0.x + acc1.x; acc.y = acc0.y + acc1.y;
  acc.z = acc0.z + acc1.z; acc.w = acc0.w + acc1.w;
  float rdenom = (deg > 0) ? (1.0f / wsum) : 0.f;
  const float4 b = *(const float4*)(bias + lane * 4);
  acc.x = fmaf(acc.x, rdenom, b.x);
  acc.y = fmaf(acc.y, rdenom, b.y);
  acc.z = fmaf(acc.z, rdenom, b.z);
  acc.w = fmaf(acc.w, rdenom, b.w);
  if (RELU) {
    acc.x = fmaxf(acc.x, 0.f); acc.y = fmaxf(acc.y, 0.f);
    acc.z = fmaxf(acc.z, 0.f); acc.w = fmaxf(acc.w, 0.f);
  }
  ushort4 o;
  o.x = f2bf(acc.x); o.y = f2bf(acc.y); o.z = f2bf(acc.z); o.w = f2bf(acc.w);
  *(ushort4*)(out + (size_t)v * FDIM + lane * 4) = o;
}

// ---------------- segmented per-graph sum pool ----------------
// 512 blocks x 256 threads; thread t owns channel t (512 B coalesced row reads);
// block covers ~98 contiguous nodes; graph runs bounded via gstart (nodes sorted);
// 4 independent register partials per run; ONE atomicAdd per thread per run
// (~150K atomics total vs 1.6M in the wave-chunk version -> no L2 serialization).
__global__ void pool_sum_kernel(const unsigned short* __restrict__ h2,
                                const int* __restrict__ n2g, const int* __restrict__ gstart,
                                float* __restrict__ hg, int nnodes) {
  int t = threadIdx.x;   // channel
  int n0 = blockIdx.x * POOL_PER;
  if (n0 >= nnodes) return;
  int n1 = min(n0 + POOL_PER, nnodes);
  int n = n0;
  while (n < n1) {
    int g = n2g[n];                    // uniform (broadcast) load
    int e = min(n1, gstart[g + 1]);
    float s0 = 0.f, s1 = 0.f, s2 = 0.f, s3 = 0.f;
    for (; n + 4 <= e; n += 4) {
      s0 += b2f(h2[(size_t)(n + 0) * FDIM + t]);
      s1 += b2f(h2[(size_t)(n + 1) * FDIM + t]);
      s2 += b2f(h2[(size_t)(n + 2) * FDIM + t]);
      s3 += b2f(h2[(size_t)(n + 3) * FDIM + t]);
    }
    for (; n < e; ++n) s0 += b2f(h2[(size_t)n * FDIM + t]);
    atomicAdd(&hg[(size_t)g * FDIM + t], (s0 + s1) + (s2 + s3));
  }
}

// ---------------- classifier (divides pooled sums by per-graph count) ----------------
__global__ void classifier_kernel(const float* __restrict__ hgsum, const int* __restrict__ gstart,
                                  const float* __restrict__ Wc, const float* __restrict__ bcv,
                                  float* __restrict__ out) {
  int tid = blockIdx.x * blockDim.x + threadIdx.x;
  if (tid >= N_GRAPHS * NC) return;
  int b = tid / NC, j = tid % NC;
  int cnt = gstart[b + 1] - gstart[b];
  float inv = (cnt > 0) ? (1.0f / (float)cnt) : 1.0f;
  float s = 0.f;
  for (int c = 0; c < FDIM; ++c) s += hgsum[b * FDIM + c] * Wc[c * NC + j];
  out[tid] = s * inv + bcv[j];
}

extern "C" void kernel_launch(void* const* d_in, const int* in_sizes, int n_in,
                              void* d_out, int out_size, void* d_ws, size_t ws_size,
                              hipStream_t stream) {
  const float* feat = (const float*)d_in[0];
  const int* src    = (const int*)d_in[1];
  const int* dst    = (const int*)d_in[2];
  const int* n2g    = (const int*)d_in[3];
  const float* W1  = (const float*)d_in[4];
  const float* al1 = (const float*)d_in[5];
  const float* ar1 = (const float*)d_in[6];
  const float* b1  = (const float*)d_in[7];
  const float* W2  = (const float*)d_in[8];
  const float* al2 = (const float*)d_in[9];
  const float* ar2 = (const float*)d_in[10];
  const float* b2  = (const float*)d_in[11];
  const float* Wc  = (const float*)d_in[12];
  const float* bc  = (const float*)d_in[13];
  float* out = (float*)d_out;

  char* wp = (char*)d_ws;
  auto carve = [&](size_t bytes) -> void* {
    void* p = (void*)wp;
    wp += (bytes + 255) & ~(size_t)255;
    return p;
  };
  unsigned char* fs = (unsigned char*)carve((size_t)MPAD * FDIM);        // 12.8 MB fp8 (padded)
  // h1/h2 share one bf16 buffer (h1 dead after gemm-2 consumes it)
  unsigned short* h1 = (unsigned short*)carve((size_t)MPAD * FDIM * 2);  // 25.6 MB bf16
  unsigned short* h2 = h1;
  unsigned short* Wt1 = (unsigned short*)carve((size_t)256 * 128 * 2);
  unsigned short* Wt2 = (unsigned short*)carve((size_t)256 * 256 * 2);
  float* el      = (float*)carve((size_t)MPAD * NHEAD * 4);
  float* er      = (float*)carve((size_t)MPAD * NHEAD * 4);
  int* rowstart  = (int*)  carve((size_t)(N_NODES + 1) * 4);
  int* esrc      = (int*)  carve((size_t)N_EDGES * 4);
  int* gstart    = (int*)  carve((size_t)(N_GRAPHS + 1) * 4);
  int* bsum      = (int*)  carve((size_t)SCAN_NB * 4);
  // zero-init region: cursor + cursor2 + hg carved contiguously, single memset
  int* cursor    = (int*)  carve((size_t)N_NODES * 4);
  int* cursor2   = (int*)  carve((size_t)N_NODES * 4);
  float* hg      = (float*)carve((size_t)N_GRAPHS * FDIM * 4);
  size_t zlen = (size_t)((char*)(hg + N_GRAPHS * FDIM) - (char*)cursor);
  (void)ws_size; (void)n_in; (void)in_sizes; (void)out_size;

  // CSR build + weight prep
  hipMemsetAsync(cursor, 0, zlen, stream);   // cursor, cursor2, hg
  hist_cast_kernel<<<(N_EDGES + 255) / 256, 256, 0, stream>>>(dst, cursor, W1, W2, Wt1, Wt2, N_EDGES);
  scan_local_kernel<<<SCAN_NB, 256, 0, stream>>>(cursor, rowstart, bsum, N_NODES);
  scan_add_gb_kernel<<<(N_NODES + 255) / 256, 256, 0, stream>>>(rowstart, bsum, n2g, gstart, N_NODES);
  scatter_kernel<<<(N_EDGES + 255) / 256, 256, 0, stream>>>(src, dst, rowstart, cursor2, esrc, N_EDGES);

  // layer 1 (gemm stages fp32 feat directly; writes fs(fp8) + el + er)
  gemm_mfma<128, true><<<MPAD / 64, 256, 0, stream>>>(
      (const void*)feat, Wt1, fs, al1, ar1, el, er, N_NODES);
  edge_agg_kernel<true><<<(N_NODES * 64 + 255) / 256, 256, 0, stream>>>(
      rowstart, esrc, el, er, fs, b1, h1, N_NODES);

  // layer 2
  gemm_mfma<256, false><<<MPAD / 64, 256, 0, stream>>>(
      (const void*)h1, Wt2, fs, al2, ar2, el, er, N_NODES);
  edge_agg_kernel<false><<<(N_NODES * 64 + 255) / 256, 256, 0, stream>>>(
      rowstart, esrc, el, er, fs, b2, h2, N_NODES);

  // readout: segmented pool (thread-per-channel, run-level atomics) + classifier
  pool_sum_kernel<<<POOL_NB, 256, 0, stream>>>(h2, n2g, gstart, hg, N_NODES);
  classifier_kernel<<<(N_GRAPHS * NC + 255) / 256, 256, 0, stream>>>(hg, gstart, Wc, bc, out);
}